// Round 1
// baseline (1259.766 us; speedup 1.0000x reference)
//
#include <hip/hip_runtime.h>

// Fused 4-layer GCN (SMPL 24-joint tree), B=65536, fp32 exact.
// Layout: G=8 batch elems / block, 512 threads (8 waves), all state in LDS.
//   A  [24][65][8]  : linear inputs  (node stride 520 words; pad kills
//                     cross-node-group bank aliasing, keeps 16B alignment)
//   Bf [24][8][68]  : linear outputs (b-stride 68 words -> <=2-way banks)
// Linear: lane = out-feature, weights in 64 VGPRs, activations broadcast via
// uniform ds_read_b128 (8 independent FMA chains / i-step).
// Agg: hard-coded tree adjacency (<=5 padded neighbors, mask-multiplied).

#define NN 24
#define W  64
#define FIN 7
#define OW 13
#define G  8
#define NT 512

__constant__ int NEI5[NN][5] = {
  {0,1,2,3,0},   {1,0,4,1,1},   {2,0,5,2,2},   {3,0,6,3,3},
  {4,1,7,4,4},   {5,2,8,5,5},   {6,3,9,6,6},   {7,4,10,7,7},
  {8,5,11,8,8},  {9,6,12,13,14},{10,7,10,10,10},{11,8,11,11,11},
  {12,9,15,12,12},{13,9,16,13,13},{14,9,17,14,14},{15,12,15,15,15},
  {16,13,18,16,16},{17,14,19,17,17},{18,16,20,18,18},{19,17,21,19,19},
  {20,18,22,20,20},{21,19,23,21,21},{22,20,22,22,22},{23,21,23,23,23}
};
__constant__ float VM5[NN][5] = {
  {1,1,1,1,0},{1,1,1,0,0},{1,1,1,0,0},{1,1,1,0,0},
  {1,1,1,0,0},{1,1,1,0,0},{1,1,1,0,0},{1,1,1,0,0},
  {1,1,1,0,0},{1,1,1,1,1},{1,1,0,0,0},{1,1,0,0,0},
  {1,1,1,0,0},{1,1,1,0,0},{1,1,1,0,0},{1,1,0,0,0},
  {1,1,1,0,0},{1,1,1,0,0},{1,1,1,0,0},{1,1,1,0,0},
  {1,1,1,0,0},{1,1,1,0,0},{1,1,0,0,0},{1,1,0,0,0}
};

typedef float (&ABuf)[NN][W+1][G];
typedef float (&BBuf)[NN][G][W+4];

template<int K>
__device__ __forceinline__ void linearK(const float* __restrict__ wm,
                                        int lane, int wv, ABuf A, BBuf Bf)
{
  // 3 rounds x 8 waves = 24 nodes; each wave: node n, 64 outputs (lane), 8 batches
  #pragma unroll 1
  for (int r = 0; r < 3; ++r) {
    const int n = r * 8 + wv;
    float wreg[K];
    #pragma unroll
    for (int i = 0; i < K; ++i) wreg[i] = wm[(n * K + i) * W + lane];
    float a0=0.f,a1=0.f,a2=0.f,a3=0.f,a4=0.f,a5=0.f,a6=0.f,a7=0.f;
    #pragma unroll
    for (int i = 0; i < K; ++i) {
      const float4 lo = *(const float4*)&A[n][i][0];   // uniform -> broadcast
      const float4 hi = *(const float4*)&A[n][i][4];
      const float ww = wreg[i];
      a0 = fmaf(lo.x, ww, a0); a1 = fmaf(lo.y, ww, a1);
      a2 = fmaf(lo.z, ww, a2); a3 = fmaf(lo.w, ww, a3);
      a4 = fmaf(hi.x, ww, a4); a5 = fmaf(hi.y, ww, a5);
      a6 = fmaf(hi.z, ww, a6); a7 = fmaf(hi.w, ww, a7);
    }
    Bf[n][0][lane]=a0; Bf[n][1][lane]=a1; Bf[n][2][lane]=a2; Bf[n][3][lane]=a3;
    Bf[n][4][lane]=a4; Bf[n][5][lane]=a5; Bf[n][6][lane]=a6; Bf[n][7][lane]=a7;
  }
}

__device__ __forceinline__ void aggL(const float* __restrict__ aw,
                                     const float* __restrict__ bias,
                                     bool do_relu, int lane, int wv,
                                     ABuf A, BBuf Bf)
{
  const int og = lane & 7;        // output-feature subgroup
  const int bb = lane >> 3;       // batch 0..7
  float bs[8];
  #pragma unroll
  for (int k = 0; k < 8; ++k) bs[k] = bias[og + 8 * k];
  #pragma unroll 1
  for (int mi = 0; mi < 3; ++mi) {
    const int m = wv * 3 + mi;    // 8 waves x 3 = 24 output nodes
    int   nidx[5];
    float sw[5];
    #pragma unroll
    for (int j = 0; j < 5; ++j) {
      nidx[j] = NEI5[m][j];
      sw[j]   = VM5[m][j] * aw[m * NN + nidx[j]];
    }
    #pragma unroll
    for (int k = 0; k < 8; ++k) {
      const int o = og + 8 * k;
      float v = bs[k];
      #pragma unroll
      for (int j = 0; j < 5; ++j)
        v = fmaf(sw[j], Bf[nidx[j]][bb][o], v);
      if (do_relu) v = fmaxf(v, 0.f);
      A[m][o][bb] = v;            // banks: 8*og+bb (+64k) -> conflict-free
    }
  }
}

__device__ __forceinline__ void linear3f(const float* __restrict__ w3,
                                         int lane, int wv, ABuf A, BBuf Bf)
{
  if (wv >= 6) return;            // 6 waves x 4 nodes = 24
  const int grp = lane >> 4;      // node within wave's group of 4
  const int o   = lane & 15;      // output feature, valid < 13
  const int oo  = (o < OW) ? o : 0;
  const int n   = wv * 4 + grp;
  float wreg[W];
  #pragma unroll
  for (int i = 0; i < W; ++i) wreg[i] = w3[(n * W + i) * OW + oo];
  float a0=0.f,a1=0.f,a2=0.f,a3=0.f,a4=0.f,a5=0.f,a6=0.f,a7=0.f;
  #pragma unroll
  for (int i = 0; i < W; ++i) {
    const float4 lo = *(const float4*)&A[n][i][0]; // 4 distinct addrs/wave;
    const float4 hi = *(const float4*)&A[n][i][4]; // 520-word node stride ->
    const float ww = wreg[i];                      // disjoint bank quads
    a0 = fmaf(lo.x, ww, a0); a1 = fmaf(lo.y, ww, a1);
    a2 = fmaf(lo.z, ww, a2); a3 = fmaf(lo.w, ww, a3);
    a4 = fmaf(hi.x, ww, a4); a5 = fmaf(hi.y, ww, a5);
    a6 = fmaf(hi.z, ww, a6); a7 = fmaf(hi.w, ww, a7);
  }
  if (o < OW) {
    Bf[n][0][o]=a0; Bf[n][1][o]=a1; Bf[n][2][o]=a2; Bf[n][3][o]=a3;
    Bf[n][4][o]=a4; Bf[n][5][o]=a5; Bf[n][6][o]=a6; Bf[n][7][o]=a7;
  }
}

extern "C" __global__ __launch_bounds__(NT, 2)
void gnn_fused(const float* __restrict__ x,
               const float* __restrict__ w0, const float* __restrict__ w1,
               const float* __restrict__ w2, const float* __restrict__ w3,
               const float* __restrict__ aw0, const float* __restrict__ aw1,
               const float* __restrict__ aw2, const float* __restrict__ aw3,
               const float* __restrict__ b0, const float* __restrict__ b1,
               const float* __restrict__ b2, const float* __restrict__ b3,
               float* __restrict__ out)
{
  __shared__ __align__(16) float A [NN][W + 1][G];   // 49,920 B
  __shared__ __align__(16) float Bf[NN][G][W + 4];   // 52,224 B  (total ~100 KB)

  const int t    = threadIdx.x;
  const int lane = t & 63;
  const int wv   = t >> 6;
  const long base = (long)blockIdx.x * G;

  // ---- load x (8 x 24 x 7), zero root node input ----
  for (int idx = t; idx < G * NN * FIN; idx += NT) {
    const int b = idx / (NN * FIN);
    const int r = idx - b * (NN * FIN);
    const int n = r / FIN;
    const int i = r - n * FIN;
    float v = x[base * (NN * FIN) + idx];   // coalesced: contiguous idx
    A[n][i][b] = (n == 0) ? 0.f : v;
  }
  __syncthreads();

  linearK<FIN>(w0, lane, wv, A, Bf);            __syncthreads();
  aggL(aw0, b0, true, lane, wv, A, Bf);         __syncthreads();
  linearK<W>(w1, lane, wv, A, Bf);              __syncthreads();
  aggL(aw1, b1, true, lane, wv, A, Bf);         __syncthreads();
  linearK<W>(w2, lane, wv, A, Bf);              __syncthreads();
  aggL(aw2, b2, true, lane, wv, A, Bf);         __syncthreads();
  linear3f(w3, lane, wv, A, Bf);                __syncthreads();

  // ---- layer-3 aggregation + bias (no relu) fused with global store ----
  for (int idx = t; idx < G * NN * OW; idx += NT) {
    const int b = idx / (NN * OW);
    const int r = idx - b * (NN * OW);
    const int m = r / OW;
    const int o = r - m * OW;
    float v = b3[o];
    #pragma unroll
    for (int j = 0; j < 5; ++j) {
      const int n = NEI5[m][j];
      v = fmaf(VM5[m][j] * aw3[m * NN + n], Bf[n][b][o], v);
    }
    out[base * (NN * OW) + idx] = v;            // coalesced: contiguous idx
  }
}

extern "C" void kernel_launch(void* const* d_in, const int* in_sizes, int n_in,
                              void* d_out, int out_size, void* d_ws, size_t ws_size,
                              hipStream_t stream)
{
  const float* x   = (const float*)d_in[0];
  const float* w0  = (const float*)d_in[1];
  const float* w1  = (const float*)d_in[2];
  const float* w2  = (const float*)d_in[3];
  const float* w3  = (const float*)d_in[4];
  const float* aw0 = (const float*)d_in[5];
  const float* aw1 = (const float*)d_in[6];
  const float* aw2 = (const float*)d_in[7];
  const float* aw3 = (const float*)d_in[8];
  const float* b0  = (const float*)d_in[9];
  const float* b1  = (const float*)d_in[10];
  const float* b2  = (const float*)d_in[11];
  const float* b3  = (const float*)d_in[12];
  float* out = (float*)d_out;

  const int B = in_sizes[0] / (NN * FIN);      // 65536
  const int grid = B / G;                      // 8192 blocks
  gnn_fused<<<grid, NT, 0, stream>>>(x, w0, w1, w2, w3,
                                     aw0, aw1, aw2, aw3,
                                     b0, b1, b2, b3, out);
}

// Round 2
// 811.929 us; speedup vs baseline: 1.5516x; 1.5516x over previous
//
#include <hip/hip_runtime.h>

// Fused 4-layer GCN (SMPL 24-joint tree) via bf16 split-3 MFMA.
// prep kernel: reformat w0..w3 into MFMA B-fragment order (hi/lo bf16 planes) in d_ws.
// main kernel: MB=16 batches/block, 512 thr (8 waves x 3 nodes).
//   LDS: act hi/lo planes AH/AL[24][16][72] bf16 (stride 72 elems = 144B, 16B aligned);
//        HX[24][4][256] u32 (hi16|lo16 packed h) aliased over AH/AL (phase-separated).
//   Linear: h = (Ah+Al)(Bh+Bl) ~= AhBh + AlBh + AhBl  (3 MFMAs, fp32 accum -> ~1e-4 rel)
//   Agg: fp32 VALU on elementwise-aligned C-frags via HX; tree adjacency in constants.

#define NN 24
#define MB 16
#define NT 512

typedef short bf16x8 __attribute__((ext_vector_type(8)));
typedef float f32x4 __attribute__((ext_vector_type(4)));

__constant__ int NEI5c[NN][5] = {
  {0,1,2,3,0},   {1,0,4,1,1},   {2,0,5,2,2},   {3,0,6,3,3},
  {4,1,7,4,4},   {5,2,8,5,5},   {6,3,9,6,6},   {7,4,10,7,7},
  {8,5,11,8,8},  {9,6,12,13,14},{10,7,10,10,10},{11,8,11,11,11},
  {12,9,15,12,12},{13,9,16,13,13},{14,9,17,14,14},{15,12,15,15,15},
  {16,13,18,16,16},{17,14,19,17,17},{18,16,20,18,18},{19,17,21,19,19},
  {20,18,22,20,20},{21,19,23,21,21},{22,20,22,22,22},{23,21,23,23,23}
};
__constant__ int DEGc[NN] = {4,3,3,3,3,3,3,3,3,5,2,2,3,3,3,2,3,3,3,3,3,3,2,2};

__device__ __forceinline__ unsigned short f2bf(float f) {
  unsigned u = __float_as_uint(f);
  u = (u + 0x7FFFu + ((u >> 16) & 1u)) >> 16;
  return (unsigned short)u;
}
__device__ __forceinline__ unsigned packhl(float v) {
  unsigned short h = f2bf(v);
  float hf = __uint_as_float(((unsigned)h) << 16);
  unsigned short l = f2bf(v - hf);
  return (((unsigned)h) << 16) | (unsigned)l;
}

// ---------------- prep: weights -> B-fragment order in ws ----------------
// dword layout (contiguous): BW0[24][1][4][2][64][4]  dwords 0      .. 49151
//                            BW1[24][2][4][2][64][4]         49152 .. 147455
//                            BW2[24][2][4][2][64][4]        147456 .. 245759
//                            BW3[24][2][1][2][64][4]        245760 .. 270335
// element j=2*dw+e of lane's frag = w[k = kh*32 + 8*(lane>>4) + j][o = ot*16 + (lane&15)]
#define PREP_TOT 270336

extern "C" __global__ void gnn_prep(const float* __restrict__ w0, const float* __restrict__ w1,
                                    const float* __restrict__ w2, const float* __restrict__ w3,
                                    unsigned* __restrict__ dst)
{
  int idx = blockIdx.x * 256 + threadIdx.x;
  if (idx >= PREP_TOT) return;
  const float* w; int KH, OT, kd, od, local;
  if (idx < 49152)       { local = idx;          w = w0; KH = 1; OT = 4; kd = 7;  od = 64; }
  else if (idx < 147456) { local = idx - 49152;  w = w1; KH = 2; OT = 4; kd = 64; od = 64; }
  else if (idx < 245760) { local = idx - 147456; w = w2; KH = 2; OT = 4; kd = 64; od = 64; }
  else                   { local = idx - 245760; w = w3; KH = 2; OT = 1; kd = 64; od = 13; }
  int per_n = KH * OT * 2 * 64 * 4;
  int n  = local / per_n;   int r = local % per_n;
  int kh = r / (OT * 512);  r %= OT * 512;
  int ot = r / 512;         r %= 512;
  int p  = r / 256;         r %= 256;
  int lane = r / 4;         int dw = r % 4;
  int o = ot * 16 + (lane & 15);
  unsigned outw = 0;
  #pragma unroll
  for (int e = 0; e < 2; ++e) {
    int k = kh * 32 + 8 * (lane >> 4) + dw * 2 + e;
    float v = (k < kd && o < od) ? w[(n * kd + k) * od + o] : 0.f;
    unsigned short hv = f2bf(v);
    unsigned short val;
    if (p == 0) val = hv;
    else { float hf = __uint_as_float(((unsigned)hv) << 16); val = f2bf(v - hf); }
    outw |= ((unsigned)val) << (16 * e);
  }
  dst[idx] = outw;
}

// ---------------- main ----------------
template<int KH, int OT, bool RELU, bool LAST>
__device__ __forceinline__ void layerF(const unsigned* __restrict__ bw,
                                       const float* __restrict__ aw,
                                       const float* __restrict__ bias,
                                       unsigned short* AH, unsigned short* AL, unsigned* HX,
                                       int lane, int wv, float* __restrict__ out, long base)
{
  const int c15 = lane & 15, g = lane >> 4;
  const bf16x8* __restrict__ bp = (const bf16x8*)bw;
  f32x4 acc[3][OT];

  // Phase A: per-node linears (MFMA, split-3)
  #pragma unroll
  for (int i = 0; i < 3; ++i) {
    const int n = wv * 3 + i;
    // hoist all B frags for this node (global, L2-resident) so loads issue early
    bf16x8 bh[KH][OT], bl[KH][OT];
    #pragma unroll
    for (int kh = 0; kh < KH; ++kh)
      #pragma unroll
      for (int ot = 0; ot < OT; ++ot) {
        int fi = (((n * KH + kh) * OT + ot) * 2) * 64 + lane;
        bh[kh][ot] = bp[fi];
        bl[kh][ot] = bp[fi + 64];
      }
    // A frags (LDS)
    bf16x8 ah[KH], al[KH];
    #pragma unroll
    for (int kh = 0; kh < KH; ++kh) {
      int aoff = (n * 16 + c15) * 72 + kh * 32 + 8 * g;
      ah[kh] = *(const bf16x8*)&AH[aoff];
      al[kh] = *(const bf16x8*)&AL[aoff];
    }
    #pragma unroll
    for (int ot = 0; ot < OT; ++ot) {
      f32x4 c = {0.f, 0.f, 0.f, 0.f};
      #pragma unroll
      for (int kh = 0; kh < KH; ++kh) {
        c = __builtin_amdgcn_mfma_f32_16x16x32_bf16(ah[kh], bh[kh][ot], c, 0, 0, 0);
        c = __builtin_amdgcn_mfma_f32_16x16x32_bf16(al[kh], bh[kh][ot], c, 0, 0, 0);
        c = __builtin_amdgcn_mfma_f32_16x16x32_bf16(ah[kh], bl[kh][ot], c, 0, 0, 0);
      }
      acc[i][ot] = c;
    }
  }
  __syncthreads();           // all A-reads done; HX may now clobber AH/AL

  // Phase B: publish h as (hi|lo)-packed u32 C-frags
  #pragma unroll
  for (int i = 0; i < 3; ++i) {
    const int n = wv * 3 + i;
    #pragma unroll
    for (int ot = 0; ot < OT; ++ot) {
      uint4 u;
      u.x = packhl(acc[i][ot][0]); u.y = packhl(acc[i][ot][1]);
      u.z = packhl(acc[i][ot][2]); u.w = packhl(acc[i][ot][3]);
      *(uint4*)&HX[(n * 4 + ot) * 256 + lane * 4] = u;
    }
  }
  __syncthreads();

  // Phase C: tree aggregation (fp32 VALU, elementwise on frags)
  f32x4 st[3][OT];
  #pragma unroll
  for (int i = 0; i < 3; ++i) {
    const int m = wv * 3 + i;
    const int deg = DEGc[m];
    #pragma unroll
    for (int ot = 0; ot < OT; ++ot) {
      float bv = LAST ? bias[c15 < 13 ? c15 : 0] : bias[ot * 16 + c15];
      f32x4 a = {bv, bv, bv, bv};
      for (int j = 0; j < deg; ++j) {          // wave-uniform trip count
        int nb = NEI5c[m][j];
        float sw = aw[m * NN + nb];
        uint4 u = *(const uint4*)&HX[(nb * 4 + ot) * 256 + lane * 4];
        a[0] = fmaf(sw, __uint_as_float(u.x & 0xFFFF0000u), a[0]);
        a[0] = fmaf(sw, __uint_as_float(u.x << 16), a[0]);
        a[1] = fmaf(sw, __uint_as_float(u.y & 0xFFFF0000u), a[1]);
        a[1] = fmaf(sw, __uint_as_float(u.y << 16), a[1]);
        a[2] = fmaf(sw, __uint_as_float(u.z & 0xFFFF0000u), a[2]);
        a[2] = fmaf(sw, __uint_as_float(u.z << 16), a[2]);
        a[3] = fmaf(sw, __uint_as_float(u.w & 0xFFFF0000u), a[3]);
        a[3] = fmaf(sw, __uint_as_float(u.w << 16), a[3]);
      }
      if (RELU) {
        a[0] = fmaxf(a[0], 0.f); a[1] = fmaxf(a[1], 0.f);
        a[2] = fmaxf(a[2], 0.f); a[3] = fmaxf(a[3], 0.f);
      }
      st[i][ot] = a;
    }
  }
  __syncthreads();           // all HX reads done; act planes may be rewritten

  // Phase D: write next-layer act (hi/lo planes) or final store
  if (!LAST) {
    #pragma unroll
    for (int i = 0; i < 3; ++i) {
      const int n = wv * 3 + i;
      #pragma unroll
      for (int ot = 0; ot < OT; ++ot)
        #pragma unroll
        for (int r = 0; r < 4; ++r) {
          float v = st[i][ot][r];
          int b = 4 * g + r, o = ot * 16 + c15;
          unsigned short h = f2bf(v);
          float hf = __uint_as_float(((unsigned)h) << 16);
          unsigned short l = f2bf(v - hf);
          AH[(n * 16 + b) * 72 + o] = h;
          AL[(n * 16 + b) * 72 + o] = l;
        }
    }
    __syncthreads();
  } else {
    if (c15 < 13) {
      #pragma unroll
      for (int i = 0; i < 3; ++i)
        #pragma unroll
        for (int r = 0; r < 4; ++r)
          out[(base + 4 * g + r) * 312 + (wv * 3 + i) * 13 + c15] = st[i][0][r];
    }
  }
}

extern "C" __global__ __launch_bounds__(NT, 2)
void gnn_main(const float* __restrict__ x,
              const float* __restrict__ aw0, const float* __restrict__ aw1,
              const float* __restrict__ aw2, const float* __restrict__ aw3,
              const float* __restrict__ b0, const float* __restrict__ b1,
              const float* __restrict__ b2, const float* __restrict__ b3,
              const unsigned* __restrict__ bw, float* __restrict__ out)
{
  __shared__ __align__(16) unsigned char LB[110592];
  unsigned short* AH = (unsigned short*)LB;             // [24][16][72] bf16 hi
  unsigned short* AL = (unsigned short*)(LB + 55296);   // [24][16][72] bf16 lo
  unsigned*       HX = (unsigned*)LB;                   // [24][4][256] u32 (aliased)

  const int t = threadIdx.x, lane = t & 63, wv = t >> 6;
  const long base = (long)blockIdx.x * MB;

  // stage x -> act planes (root masked); zero k = 7..31 pad (L0 reads k<32)
  for (int i = t; i < MB * NN * 7; i += NT) {
    int b = i / 168, r = i % 168, n = r / 7, k = r % 7;
    float v = x[base * 168 + i];
    if (n == 0) v = 0.f;
    unsigned short h = f2bf(v);
    float hf = __uint_as_float(((unsigned)h) << 16);
    unsigned short l = f2bf(v - hf);
    AH[(n * 16 + b) * 72 + k] = h;
    AL[(n * 16 + b) * 72 + k] = l;
  }
  for (int i = t; i < NN * MB * 25; i += NT) {
    int n = i / 400, r = i % 400, b = r / 25, k = 7 + r % 25;
    AH[(n * 16 + b) * 72 + k] = 0;
    AL[(n * 16 + b) * 72 + k] = 0;
  }
  __syncthreads();

  layerF<1, 4, true,  false>(bw + 0,      aw0, b0, AH, AL, HX, lane, wv, out, base);
  layerF<2, 4, true,  false>(bw + 49152, aw1, b1, AH, AL, HX, lane, wv, out, base);
  layerF<2, 4, true,  false>(bw + 147456, aw2, b2, AH, AL, HX, lane, wv, out, base);
  layerF<2, 1, false, true >(bw + 245760, aw3, b3, AH, AL, HX, lane, wv, out, base);
}

extern "C" void kernel_launch(void* const* d_in, const int* in_sizes, int n_in,
                              void* d_out, int out_size, void* d_ws, size_t ws_size,
                              hipStream_t stream)
{
  const float* x   = (const float*)d_in[0];
  const float* w0  = (const float*)d_in[1];
  const float* w1  = (const float*)d_in[2];
  const float* w2  = (const float*)d_in[3];
  const float* w3  = (const float*)d_in[4];
  const float* aw0 = (const float*)d_in[5];
  const float* aw1 = (const float*)d_in[6];
  const float* aw2 = (const float*)d_in[7];
  const float* aw3 = (const float*)d_in[8];
  const float* b0  = (const float*)d_in[9];
  const float* b1  = (const float*)d_in[10];
  const float* b2  = (const float*)d_in[11];
  const float* b3  = (const float*)d_in[12];
  float* out = (float*)d_out;
  unsigned* bw = (unsigned*)d_ws;          // needs PREP_TOT*4 = 1,081,344 B of ws

  const int B = in_sizes[0] / (NN * 7);    // 65536
  const int grid = B / MB;                 // 4096

  gnn_prep<<<(PREP_TOT + 255) / 256, 256, 0, stream>>>(w0, w1, w2, w3, bw);
  gnn_main<<<grid, NT, 0, stream>>>(x, aw0, aw1, aw2, aw3, b0, b1, b2, b3, bw, out);
}

// Round 3
// 552.435 us; speedup vs baseline: 2.2804x; 1.4697x over previous
//
#include <hip/hip_runtime.h>

// Fused 4-layer GCN (SMPL 24-joint tree), bf16 split-3 MFMA, round 3.
// Changes vs round 2 (theory: kill exchange VALU + vectorize DS):
//  - swapped MFMA operands: D = w^T-frag x act-frag -> lane owns 4 consecutive
//    output features => ds_write_b64 act writes, float4 HX ops
//  - exchange buffer HX is raw fp32 (same bytes as packed u32, zero pack VALU)
//  - truncation hi/lo split (shift/and; residual 2^-16 rel)
//  - act planes stride 64 + XOR swizzle ((b&7)<<4): all DS <=2-way conflicts
//  - HX aliased over act planes (dead after phase A reads), LDS = 104448 B

#define NN 24
#define MB 16
#define NT 512
#define PREP_TOT 270336

typedef short bf16x8 __attribute__((ext_vector_type(8)));
typedef float f32x4 __attribute__((ext_vector_type(4)));

__constant__ int NEI5c[NN][5] = {
  {0,1,2,3,0},   {1,0,4,1,1},   {2,0,5,2,2},   {3,0,6,3,3},
  {4,1,7,4,4},   {5,2,8,5,5},   {6,3,9,6,6},   {7,4,10,7,7},
  {8,5,11,8,8},  {9,6,12,13,14},{10,7,10,10,10},{11,8,11,11,11},
  {12,9,15,12,12},{13,9,16,13,13},{14,9,17,14,14},{15,12,15,15,15},
  {16,13,18,16,16},{17,14,19,17,17},{18,16,20,18,18},{19,17,21,19,19},
  {20,18,22,20,20},{21,19,23,21,21},{22,20,22,22,22},{23,21,23,23,23}
};
__constant__ int DEGc[NN] = {4,3,3,3,3,3,3,3,3,5,2,2,3,3,3,2,3,3,3,3,3,3,2,2};

// act plane byte offset: row = (n*16+b)*128B (64 bf16), XOR-swizzled
__device__ __forceinline__ int actoff(int n, int b, int k) {
  return (((n * 16 + b) << 7) + 2 * k) ^ ((b & 7) << 4);
}

// ---------------- prep: weights -> A-fragment (w^T) hi/lo planes ----------------
// dwords: L0 [24][1][4][2][64][4] @0      L1 [24][2][4][2][64][4] @49152
//         L2 [...] @147456               L3 [24][2][1][2][64][4] @245760
// frag element j=2*dw+e: w[k = kh*32 + 8*(lane>>4) + j][o = ot*16 + (lane&15)]
extern "C" __global__ void gnn_prep(const float* __restrict__ w0, const float* __restrict__ w1,
                                    const float* __restrict__ w2, const float* __restrict__ w3,
                                    unsigned* __restrict__ dst)
{
  int idx = blockIdx.x * 256 + threadIdx.x;
  if (idx >= PREP_TOT) return;
  const float* w; int KH, OT, kd, od, local;
  if (idx < 49152)       { local = idx;           w = w0; KH = 1; OT = 4; kd = 7;  od = 64; }
  else if (idx < 147456) { local = idx - 49152;   w = w1; KH = 2; OT = 4; kd = 64; od = 64; }
  else if (idx < 245760) { local = idx - 147456;  w = w2; KH = 2; OT = 4; kd = 64; od = 64; }
  else                   { local = idx - 245760;  w = w3; KH = 2; OT = 1; kd = 64; od = 13; }
  int per_n = KH * OT * 512;
  int n  = local / per_n;   int r = local % per_n;
  int kh = r / (OT * 512);  r %= OT * 512;
  int ot = r / 512;         r %= 512;
  int p  = r / 256;         r %= 256;
  int lane = r / 4;         int dw = r % 4;
  int o = ot * 16 + (lane & 15);
  unsigned outw = 0;
  #pragma unroll
  for (int e = 0; e < 2; ++e) {
    int k = kh * 32 + 8 * (lane >> 4) + dw * 2 + e;
    float v = (k < kd && o < od) ? w[(n * kd + k) * od + o] : 0.f;
    unsigned u = __float_as_uint(v);
    unsigned short val;
    if (p == 0) val = (unsigned short)(u >> 16);                 // trunc hi
    else {
      float hf = __uint_as_float(u & 0xFFFF0000u);
      val = (unsigned short)(__float_as_uint(v - hf) >> 16);     // trunc lo
    }
    outw |= ((unsigned)val) << (16 * e);
  }
  dst[idx] = outw;
}

// ---------------- main ----------------
template<int KH, int OT, bool RELU, bool LAST>
__device__ __forceinline__ void layerF(const unsigned* __restrict__ bw,
                                       const float* __restrict__ aw,
                                       const float* __restrict__ bias,
                                       char* AH, char* AL, float* HX,
                                       int lane, int wv,
                                       float* __restrict__ out, long base)
{
  const int c15 = lane & 15, g = lane >> 4;
  const bf16x8* __restrict__ bp = (const bf16x8*)bw;
  f32x4 acc[3][OT];

  // Phase A: per-node linears. D[row=o][col=b] = w^T x act  (split-3)
  #pragma unroll
  for (int i = 0; i < 3; ++i) {
    const int n = wv * 3 + i;
    bf16x8 wh[KH][OT], wl[KH][OT];
    #pragma unroll
    for (int kh = 0; kh < KH; ++kh)
      #pragma unroll
      for (int ot = 0; ot < OT; ++ot) {
        const int fi = (((n * KH + kh) * OT + ot) * 2) * 64 + lane;
        wh[kh][ot] = bp[fi];
        wl[kh][ot] = bp[fi + 64];
      }
    bf16x8 ah[KH], al[KH];
    #pragma unroll
    for (int kh = 0; kh < KH; ++kh) {
      const int off = actoff(n, c15, kh * 32 + 8 * g);
      ah[kh] = *(const bf16x8*)(AH + off);
      al[kh] = *(const bf16x8*)(AL + off);
    }
    #pragma unroll
    for (int ot = 0; ot < OT; ++ot) {
      f32x4 c = {0.f, 0.f, 0.f, 0.f};
      #pragma unroll
      for (int kh = 0; kh < KH; ++kh) {
        c = __builtin_amdgcn_mfma_f32_16x16x32_bf16(wh[kh][ot], ah[kh], c, 0, 0, 0);
        c = __builtin_amdgcn_mfma_f32_16x16x32_bf16(wl[kh][ot], ah[kh], c, 0, 0, 0);
        c = __builtin_amdgcn_mfma_f32_16x16x32_bf16(wh[kh][ot], al[kh], c, 0, 0, 0);
      }
      acc[i][ot] = c;
    }
  }
  __syncthreads();                     // act reads done; HX may clobber planes

  // Phase B: publish h as raw fp32 (float4, no packing)
  #pragma unroll
  for (int i = 0; i < 3; ++i) {
    const int n = wv * 3 + i;
    #pragma unroll
    for (int ot = 0; ot < OT; ++ot)
      *(f32x4*)&HX[(n * 16 + c15) * 68 + ot * 16 + 4 * g] = acc[i][ot];
  }
  __syncthreads();

  // Phase C: tree aggregation, float4 FMA
  f32x4 st[3][OT];
  #pragma unroll
  for (int i = 0; i < 3; ++i) {
    const int m = wv * 3 + i;
    #pragma unroll
    for (int ot = 0; ot < OT; ++ot) {
      f32x4 a;
      if (LAST) {
        #pragma unroll
        for (int r = 0; r < 4; ++r) {
          const int o = 4 * g + r;
          a[r] = (o < 13) ? bias[o] : 0.f;
        }
      } else {
        const float4 bv = *(const float4*)&bias[ot * 16 + 4 * g];
        a[0] = bv.x; a[1] = bv.y; a[2] = bv.z; a[3] = bv.w;
      }
      st[i][ot] = a;
    }
    const int deg = DEGc[m];
    for (int j = 0; j < deg; ++j) {            // wave-uniform trip count
      const int nb = NEI5c[m][j];
      const float sw = aw[m * NN + nb];
      #pragma unroll
      for (int ot = 0; ot < OT; ++ot) {
        const f32x4 u = *(const f32x4*)&HX[(nb * 16 + c15) * 68 + ot * 16 + 4 * g];
        st[i][ot][0] = fmaf(sw, u[0], st[i][ot][0]);
        st[i][ot][1] = fmaf(sw, u[1], st[i][ot][1]);
        st[i][ot][2] = fmaf(sw, u[2], st[i][ot][2]);
        st[i][ot][3] = fmaf(sw, u[3], st[i][ot][3]);
      }
    }
    if (RELU) {
      #pragma unroll
      for (int ot = 0; ot < OT; ++ot) {
        st[i][ot][0] = fmaxf(st[i][ot][0], 0.f);
        st[i][ot][1] = fmaxf(st[i][ot][1], 0.f);
        st[i][ot][2] = fmaxf(st[i][ot][2], 0.f);
        st[i][ot][3] = fmaxf(st[i][ot][3], 0.f);
      }
    }
  }
  __syncthreads();                     // HX dead; act planes may be rewritten

  // Phase D: write next-layer act (trunc hi/lo, b64 vectorized) or final store
  if (!LAST) {
    #pragma unroll
    for (int i = 0; i < 3; ++i) {
      const int n = wv * 3 + i;
      #pragma unroll
      for (int ot = 0; ot < OT; ++ot) {
        const unsigned u0 = __float_as_uint(st[i][ot][0]);
        const unsigned u1 = __float_as_uint(st[i][ot][1]);
        const unsigned u2 = __float_as_uint(st[i][ot][2]);
        const unsigned u3 = __float_as_uint(st[i][ot][3]);
        const float d0 = st[i][ot][0] - __uint_as_float(u0 & 0xFFFF0000u);
        const float d1 = st[i][ot][1] - __uint_as_float(u1 & 0xFFFF0000u);
        const float d2 = st[i][ot][2] - __uint_as_float(u2 & 0xFFFF0000u);
        const float d3 = st[i][ot][3] - __uint_as_float(u3 & 0xFFFF0000u);
        uint2 hv, lv;
        hv.x = (u0 >> 16) | (u1 & 0xFFFF0000u);
        hv.y = (u2 >> 16) | (u3 & 0xFFFF0000u);
        lv.x = (__float_as_uint(d0) >> 16) | (__float_as_uint(d1) & 0xFFFF0000u);
        lv.y = (__float_as_uint(d2) >> 16) | (__float_as_uint(d3) & 0xFFFF0000u);
        const int off = actoff(n, c15, ot * 16 + 4 * g);
        *(uint2*)(AH + off) = hv;
        *(uint2*)(AL + off) = lv;
      }
    }
    __syncthreads();
  } else {
    #pragma unroll
    for (int i = 0; i < 3; ++i) {
      const int m = wv * 3 + i;
      float* po = out + (base + c15) * 312 + m * 13;
      #pragma unroll
      for (int r = 0; r < 4; ++r) {
        const int o = 4 * g + r;
        if (o < 13) po[o] = st[i][0][r];
      }
    }
  }
}

extern "C" __global__ __launch_bounds__(NT, 2)
void gnn_main(const float* __restrict__ x,
              const float* __restrict__ aw0, const float* __restrict__ aw1,
              const float* __restrict__ aw2, const float* __restrict__ aw3,
              const float* __restrict__ b0, const float* __restrict__ b1,
              const float* __restrict__ b2, const float* __restrict__ b3,
              const unsigned* __restrict__ bw, float* __restrict__ out)
{
  __shared__ __align__(16) unsigned char LB[104448];
  char*  AH = (char*)LB;               // [24][16][64] bf16 hi, XOR-swizzled
  char*  AL = (char*)LB + 49152;       // [24][16][64] bf16 lo
  float* HX = (float*)LB;              // [24][16][68] fp32 (aliased, phase-sep)

  const int t = threadIdx.x, lane = t & 63, wv = t >> 6;
  const long base = (long)blockIdx.x * MB;

  // stage x -> act planes (root masked, trunc split)
  for (int i2 = t; i2 < MB * NN * 7; i2 += NT) {
    const int b = i2 / 168, r = i2 % 168, n = r / 7, k = r % 7;
    float v = x[base * 168 + i2];                 // coalesced
    if (n == 0) v = 0.f;
    const unsigned u = __float_as_uint(v);
    const unsigned short h = (unsigned short)(u >> 16);
    const float hf = __uint_as_float(u & 0xFFFF0000u);
    const unsigned short l = (unsigned short)(__float_as_uint(v - hf) >> 16);
    const int off = actoff(n, b, k);
    *(unsigned short*)(AH + off) = h;
    *(unsigned short*)(AL + off) = l;
  }
  // zero k = 7..31 (layer-0 K window; avoids stale-LDS NaN poisoning)
  for (int i2 = t; i2 < NN * MB; i2 += NT) {
    const int n = i2 / 16, b = i2 % 16;
    *(unsigned short*)(AH + actoff(n, b, 7)) = 0;
    *(unsigned short*)(AL + actoff(n, b, 7)) = 0;
    #pragma unroll
    for (int k = 8; k < 32; k += 2) {
      *(unsigned*)(AH + actoff(n, b, k)) = 0;
      *(unsigned*)(AL + actoff(n, b, k)) = 0;
    }
  }
  __syncthreads();

  layerF<1, 4, true,  false>(bw,          aw0, b0, AH, AL, HX, lane, wv, out, base);
  layerF<2, 4, true,  false>(bw + 49152,  aw1, b1, AH, AL, HX, lane, wv, out, base);
  layerF<2, 4, true,  false>(bw + 147456, aw2, b2, AH, AL, HX, lane, wv, out, base);
  layerF<2, 1, false, true >(bw + 245760, aw3, b3, AH, AL, HX, lane, wv, out, base);
}

extern "C" void kernel_launch(void* const* d_in, const int* in_sizes, int n_in,
                              void* d_out, int out_size, void* d_ws, size_t ws_size,
                              hipStream_t stream)
{
  const float* x   = (const float*)d_in[0];
  const float* w0  = (const float*)d_in[1];
  const float* w1  = (const float*)d_in[2];
  const float* w2  = (const float*)d_in[3];
  const float* w3  = (const float*)d_in[4];
  const float* aw0 = (const float*)d_in[5];
  const float* aw1 = (const float*)d_in[6];
  const float* aw2 = (const float*)d_in[7];
  const float* aw3 = (const float*)d_in[8];
  const float* b0  = (const float*)d_in[9];
  const float* b1  = (const float*)d_in[10];
  const float* b2  = (const float*)d_in[11];
  const float* b3  = (const float*)d_in[12];
  float* out = (float*)d_out;
  unsigned* bw = (unsigned*)d_ws;               // 1,081,344 B of workspace

  const int B = in_sizes[0] / (NN * 7);         // 65536
  const int grid = B / MB;                      // 4096

  gnn_prep<<<(PREP_TOT + 255) / 256, 256, 0, stream>>>(w0, w1, w2, w3, bw);
  gnn_main<<<grid, NT, 0, stream>>>(x, aw0, aw1, aw2, aw3, b0, b1, b2, b3, bw, out);
}

// Round 4
// 542.062 us; speedup vs baseline: 2.3240x; 1.0191x over previous
//
#include <hip/hip_runtime.h>

// Fused 4-layer GCN (SMPL 24-joint tree), bf16 split-3 MFMA, round 4.
// vs round 3: node-region-aliased exchange (h overwrites own act region; write
// ordered after reads by data dependency -> barriers 17->8), lgkm-only raw
// barriers (weight loads stay in flight), depth-1 next-layer weight prefetch,
// unified ((row&7)<<4) XOR swizzle on act(128B rows) and HX(256B rows).
// LDS = 24 node regions x 4096 B = 98304.

#define NN 24
#define MB 16
#define NT 512
#define PREP_TOT 270336

typedef short bf16x8 __attribute__((ext_vector_type(8)));
typedef float f32x4 __attribute__((ext_vector_type(4)));
typedef bf16x8 bf16x8_ma __attribute__((may_alias));
typedef f32x4  f32x4_ma  __attribute__((may_alias));
typedef uint2  uint2_ma  __attribute__((may_alias));
typedef unsigned       u32_ma __attribute__((may_alias));
typedef unsigned short u16_ma __attribute__((may_alias));

__constant__ int NEI5c[NN][5] = {
  {0,1,2,3,0},   {1,0,4,1,1},   {2,0,5,2,2},   {3,0,6,3,3},
  {4,1,7,4,4},   {5,2,8,5,5},   {6,3,9,6,6},   {7,4,10,7,7},
  {8,5,11,8,8},  {9,6,12,13,14},{10,7,10,10,10},{11,8,11,11,11},
  {12,9,15,12,12},{13,9,16,13,13},{14,9,17,14,14},{15,12,15,15,15},
  {16,13,18,16,16},{17,14,19,17,17},{18,16,20,18,18},{19,17,21,19,19},
  {20,18,22,20,20},{21,19,23,21,21},{22,20,22,22,22},{23,21,23,23,23}
};
__constant__ int DEGc[NN] = {4,3,3,3,3,3,3,3,3,5,2,2,3,3,3,2,3,3,3,3,3,3,2,2};

__device__ __forceinline__ void barrier_lgkm() {
  asm volatile("s_waitcnt lgkmcnt(0)" ::: "memory");
  __builtin_amdgcn_s_barrier();
  asm volatile("" ::: "memory");   // block load-hoisting above the barrier
}

// ---------------- prep: weights -> A-fragment (w^T) hi/lo planes -------------
// dwords: L0 [24][1][4][2][64][4] @0      L1 [24][2][4][2][64][4] @49152
//         L2 [...] @147456               L3 [24][2][1][2][64][4] @245760
// frag element j=2*dw+e: w[k = kh*32 + 8*(lane>>4) + j][o = ot*16 + (lane&15)]
extern "C" __global__ void gnn_prep(const float* __restrict__ w0, const float* __restrict__ w1,
                                    const float* __restrict__ w2, const float* __restrict__ w3,
                                    unsigned* __restrict__ dst)
{
  int idx = blockIdx.x * 256 + threadIdx.x;
  if (idx >= PREP_TOT) return;
  const float* w; int KH, OT, kd, od, local;
  if (idx < 49152)       { local = idx;           w = w0; KH = 1; OT = 4; kd = 7;  od = 64; }
  else if (idx < 147456) { local = idx - 49152;   w = w1; KH = 2; OT = 4; kd = 64; od = 64; }
  else if (idx < 245760) { local = idx - 147456;  w = w2; KH = 2; OT = 4; kd = 64; od = 64; }
  else                   { local = idx - 245760;  w = w3; KH = 2; OT = 1; kd = 64; od = 13; }
  int per_n = KH * OT * 512;
  int n  = local / per_n;   int r = local % per_n;
  int kh = r / (OT * 512);  r %= OT * 512;
  int ot = r / 512;         r %= 512;
  int p  = r / 256;         r %= 256;
  int lane = r / 4;         int dw = r % 4;
  int o = ot * 16 + (lane & 15);
  unsigned outw = 0;
  #pragma unroll
  for (int e = 0; e < 2; ++e) {
    int k = kh * 32 + 8 * (lane >> 4) + dw * 2 + e;
    float v = (k < kd && o < od) ? w[(n * kd + k) * od + o] : 0.f;
    unsigned u = __float_as_uint(v);
    unsigned short val;
    if (p == 0) val = (unsigned short)(u >> 16);                 // trunc hi
    else {
      float hf = __uint_as_float(u & 0xFFFF0000u);
      val = (unsigned short)(__float_as_uint(v - hf) >> 16);     // trunc lo
    }
    outw |= ((unsigned)val) << (16 * e);
  }
  dst[idx] = outw;
}

// ---------------- main ----------------
// node region n (4096 B): AH rows [16][128B] @0, AL rows @2048 (bf16 act),
// aliased as HX rows [16][256B] fp32 (phase-separated). swz = (row&7)<<4.
template<int KH, int OT, bool RELU, bool LAST, int NKH, int NOT>
__device__ __forceinline__ void layerF(const unsigned* __restrict__ bw,
                                       const unsigned* __restrict__ nbw,
                                       const float* __restrict__ aw,
                                       const float* __restrict__ bias,
                                       char* __restrict__ LB,
                                       int lane, int wv,
                                       float* __restrict__ out, long base,
                                       bf16x8* PF)
{
  const int c15 = lane & 15, g = lane >> 4;
  const int swz = (c15 & 7) << 4;
  const bf16x8* __restrict__ bp = (const bf16x8*)bw;
  f32x4 acc[3][OT];

  // Phase A: per-node linears. D[row=o][col=b] = w^T x act  (split-3)
  #pragma unroll
  for (int i = 0; i < 3; ++i) {
    const int n = wv * 3 + i;
    bf16x8 wh[KH][OT], wl[KH][OT];
    if (i == 0) {                      // prefetched during previous layer
      #pragma unroll
      for (int kh = 0; kh < KH; ++kh)
        #pragma unroll
        for (int ot = 0; ot < OT; ++ot) {
          wh[kh][ot] = PF[(kh * OT + ot) * 2];
          wl[kh][ot] = PF[(kh * OT + ot) * 2 + 1];
        }
    } else {
      #pragma unroll
      for (int kh = 0; kh < KH; ++kh)
        #pragma unroll
        for (int ot = 0; ot < OT; ++ot) {
          const int fi = (((n * KH + kh) * OT + ot) * 2) * 64 + lane;
          wh[kh][ot] = bp[fi];
          wl[kh][ot] = bp[fi + 64];
        }
    }
    bf16x8 ah[KH], al[KH];
    char* actn = LB + n * 4096 + c15 * 128;
    #pragma unroll
    for (int kh = 0; kh < KH; ++kh) {
      const int cb = (64 * kh + 16 * g) ^ swz;
      ah[kh] = *(const bf16x8_ma*)(actn + cb);
      al[kh] = *(const bf16x8_ma*)(actn + 2048 + cb);
    }
    #pragma unroll
    for (int ot = 0; ot < OT; ++ot) {
      f32x4 c = {0.f, 0.f, 0.f, 0.f};
      #pragma unroll
      for (int kh = 0; kh < KH; ++kh) {
        c = __builtin_amdgcn_mfma_f32_16x16x32_bf16(wh[kh][ot], ah[kh], c, 0, 0, 0);
        c = __builtin_amdgcn_mfma_f32_16x16x32_bf16(wl[kh][ot], ah[kh], c, 0, 0, 0);
        c = __builtin_amdgcn_mfma_f32_16x16x32_bf16(wh[kh][ot], al[kh], c, 0, 0, 0);
      }
      acc[i][ot] = c;
    }
  }

  // Phase B: publish h (fp32) into OWN node region. Ordered after phase-A
  // reads by data dependency (stored acc <- MFMA <- act reads). No barrier.
  #pragma unroll
  for (int i = 0; i < 3; ++i) {
    char* hxn = LB + (wv * 3 + i) * 4096 + c15 * 256;
    #pragma unroll
    for (int ot = 0; ot < OT; ++ot)
      *(f32x4_ma*)(hxn + ((64 * ot + 16 * g) ^ swz)) = acc[i][ot];
  }
  barrier_lgkm();

  // prefetch next layer's node-0 weight frags; in flight across C/D
  if (!LAST) {
    const bf16x8* __restrict__ np = (const bf16x8*)nbw;
    const int n0 = wv * 3;
    #pragma unroll
    for (int kh = 0; kh < NKH; ++kh)
      #pragma unroll
      for (int ot = 0; ot < NOT; ++ot) {
        const int fi = (((n0 * NKH + kh) * NOT + ot) * 2) * 64 + lane;
        PF[(kh * NOT + ot) * 2]     = np[fi];
        PF[(kh * NOT + ot) * 2 + 1] = np[fi + 64];
      }
  }

  // Phase C: tree aggregation (fp32 float4 FMA on neighbors' h)
  f32x4 st[3][OT];
  #pragma unroll
  for (int i = 0; i < 3; ++i) {
    const int m = wv * 3 + i;
    #pragma unroll
    for (int ot = 0; ot < OT; ++ot) {
      if (LAST) {
        #pragma unroll
        for (int r = 0; r < 4; ++r) {
          const int o = 4 * g + r;
          st[i][ot][r] = (o < 13) ? bias[o] : 0.f;
        }
      } else {
        const float4 bv = *(const float4*)&bias[ot * 16 + 4 * g];
        st[i][ot][0] = bv.x; st[i][ot][1] = bv.y;
        st[i][ot][2] = bv.z; st[i][ot][3] = bv.w;
      }
    }
    const int deg = DEGc[m];
    for (int j = 0; j < deg; ++j) {            // wave-uniform trip count
      const int nb = NEI5c[m][j];
      const float sw = aw[m * NN + nb];
      const char* hxn = LB + nb * 4096 + c15 * 256;
      #pragma unroll
      for (int ot = 0; ot < OT; ++ot) {
        const f32x4 u = *(const f32x4_ma*)(hxn + ((64 * ot + 16 * g) ^ swz));
        st[i][ot][0] = fmaf(sw, u[0], st[i][ot][0]);
        st[i][ot][1] = fmaf(sw, u[1], st[i][ot][1]);
        st[i][ot][2] = fmaf(sw, u[2], st[i][ot][2]);
        st[i][ot][3] = fmaf(sw, u[3], st[i][ot][3]);
      }
    }
    if (RELU) {
      #pragma unroll
      for (int ot = 0; ot < OT; ++ot) {
        st[i][ot][0] = fmaxf(st[i][ot][0], 0.f);
        st[i][ot][1] = fmaxf(st[i][ot][1], 0.f);
        st[i][ot][2] = fmaxf(st[i][ot][2], 0.f);
        st[i][ot][3] = fmaxf(st[i][ot][3], 0.f);
      }
    }
  }

  if (!LAST) {
    barrier_lgkm();                   // all C reads done before D overwrites h
    // Phase D: write next-layer act (trunc hi/lo) into OWN region; next
    // phase A reads own region only -> no trailing barrier.
    #pragma unroll
    for (int i = 0; i < 3; ++i) {
      char* actn = LB + (wv * 3 + i) * 4096 + c15 * 128;
      #pragma unroll
      for (int ot = 0; ot < OT; ++ot) {
        const unsigned u0 = __float_as_uint(st[i][ot][0]);
        const unsigned u1 = __float_as_uint(st[i][ot][1]);
        const unsigned u2 = __float_as_uint(st[i][ot][2]);
        const unsigned u3 = __float_as_uint(st[i][ot][3]);
        const float d0 = st[i][ot][0] - __uint_as_float(u0 & 0xFFFF0000u);
        const float d1 = st[i][ot][1] - __uint_as_float(u1 & 0xFFFF0000u);
        const float d2 = st[i][ot][2] - __uint_as_float(u2 & 0xFFFF0000u);
        const float d3 = st[i][ot][3] - __uint_as_float(u3 & 0xFFFF0000u);
        uint2 hv, lv;
        hv.x = (u0 >> 16) | (u1 & 0xFFFF0000u);
        hv.y = (u2 >> 16) | (u3 & 0xFFFF0000u);
        lv.x = (__float_as_uint(d0) >> 16) | (__float_as_uint(d1) & 0xFFFF0000u);
        lv.y = (__float_as_uint(d2) >> 16) | (__float_as_uint(d3) & 0xFFFF0000u);
        const int cb = (32 * ot + 8 * g) ^ swz;
        *(uint2_ma*)(actn + cb) = hv;
        *(uint2_ma*)(actn + 2048 + cb) = lv;
      }
    }
  } else {
    #pragma unroll
    for (int i = 0; i < 3; ++i) {
      const int m = wv * 3 + i;
      float* po = out + (base + c15) * 312 + m * 13;
      #pragma unroll
      for (int r = 0; r < 4; ++r) {
        const int o = 4 * g + r;
        if (o < 13) po[o] = st[i][0][r];
      }
    }
  }
}

extern "C" __global__ __launch_bounds__(NT, 2)
void gnn_main(const float* __restrict__ x,
              const float* __restrict__ aw0, const float* __restrict__ aw1,
              const float* __restrict__ aw2, const float* __restrict__ aw3,
              const float* __restrict__ b0, const float* __restrict__ b1,
              const float* __restrict__ b2, const float* __restrict__ b3,
              const unsigned* __restrict__ bw, float* __restrict__ out)
{
  __shared__ __align__(16) char LB[NN * 4096];   // 98304 B
  const int t = threadIdx.x, lane = t & 63, wv = t >> 6;
  const long base = (long)blockIdx.x * MB;

  // layer-0 node-0 weight prefetch (overlaps x staging)
  bf16x8 PF[16];
  {
    const bf16x8* __restrict__ bp = (const bf16x8*)bw;
    const int n0 = wv * 3;
    #pragma unroll
    for (int ot = 0; ot < 4; ++ot) {
      const int fi = ((n0 * 4 + ot) * 2) * 64 + lane;    // KH=1
      PF[ot * 2]     = bp[fi];
      PF[ot * 2 + 1] = bp[fi + 64];
    }
  }

  // stage x -> act planes (root masked, trunc split)
  for (int i2 = t; i2 < MB * NN * 7; i2 += NT) {
    const int b = i2 / 168, r = i2 % 168, n = r / 7, k = r % 7;
    float v = x[base * 168 + i2];                 // coalesced
    if (n == 0) v = 0.f;
    const unsigned u = __float_as_uint(v);
    const float hf = __uint_as_float(u & 0xFFFF0000u);
    const unsigned short h = (unsigned short)(u >> 16);
    const unsigned short l = (unsigned short)(__float_as_uint(v - hf) >> 16);
    char* actn = LB + n * 4096 + b * 128;
    const int cb = (2 * k) ^ ((b & 7) << 4);
    *(u16_ma*)(actn + cb) = h;
    *(u16_ma*)(actn + 2048 + cb) = l;
  }
  // zero k = 7..31 (layer-0 K window)
  for (int i2 = t; i2 < NN * MB; i2 += NT) {
    const int n = i2 / 16, b = i2 % 16;
    char* actn = LB + n * 4096 + b * 128;
    const int s = (b & 7) << 4;
    *(u16_ma*)(actn + (14 ^ s)) = 0;
    *(u16_ma*)(actn + 2048 + (14 ^ s)) = 0;
    #pragma unroll
    for (int k = 8; k < 32; k += 2) {
      const int cb = (2 * k) ^ s;
      *(u32_ma*)(actn + cb) = 0;
      *(u32_ma*)(actn + 2048 + cb) = 0;
    }
  }
  barrier_lgkm();

  layerF<1,4,true ,false,2,4>(bw,          bw + 49152,  aw0, b0, LB, lane, wv, out, base, PF);
  layerF<2,4,true ,false,2,4>(bw + 49152,  bw + 147456, aw1, b1, LB, lane, wv, out, base, PF);
  layerF<2,4,true ,false,2,1>(bw + 147456, bw + 245760, aw2, b2, LB, lane, wv, out, base, PF);
  layerF<2,1,false,true ,2,1>(bw + 245760, bw + 245760, aw3, b3, LB, lane, wv, out, base, PF);
}

extern "C" void kernel_launch(void* const* d_in, const int* in_sizes, int n_in,
                              void* d_out, int out_size, void* d_ws, size_t ws_size,
                              hipStream_t stream)
{
  const float* x   = (const float*)d_in[0];
  const float* w0  = (const float*)d_in[1];
  const float* w1  = (const float*)d_in[2];
  const float* w2  = (const float*)d_in[3];
  const float* w3  = (const float*)d_in[4];
  const float* aw0 = (const float*)d_in[5];
  const float* aw1 = (const float*)d_in[6];
  const float* aw2 = (const float*)d_in[7];
  const float* aw3 = (const float*)d_in[8];
  const float* b0  = (const float*)d_in[9];
  const float* b1  = (const float*)d_in[10];
  const float* b2  = (const float*)d_in[11];
  const float* b3  = (const float*)d_in[12];
  float* out = (float*)d_out;
  unsigned* bw = (unsigned*)d_ws;               // 1,081,344 B of workspace

  const int B = in_sizes[0] / (NN * 7);         // 65536
  const int grid = B / MB;                      // 4096

  gnn_prep<<<(PREP_TOT + 255) / 256, 256, 0, stream>>>(w0, w1, w2, w3, bw);
  gnn_main<<<grid, NT, 0, stream>>>(x, aw0, aw1, aw2, aw3, b0, b1, b2, b3, bw, out);
}

// Round 5
// 540.657 us; speedup vs baseline: 2.3301x; 1.0026x over previous
//
#include <hip/hip_runtime.h>

// Fused 4-layer GCN (SMPL 24-joint tree), bf16 split-3 MFMA, round 5.
// vs round 4: NT=1024 (16 waves, 4 waves/SIMD) by splitting each node's OT
// across wave pairs (wave w: nodes 3*(w>>1)..+2, ots {2*(w&1),2*(w&1)+1}).
// Occupancy doubles at constant LDS (98304 B, 1 block/CU). Aliasing now
// crosses the wave pair -> A->B and D->A barriers restored (lgkm-only, cheap).
// PF prefetch dropped to fit __launch_bounds__(1024,4) (<=128 VGPR).

#define NN 24
#define MB 16
#define NT 1024
#define PREP_TOT 270336

typedef short bf16x8 __attribute__((ext_vector_type(8)));
typedef float f32x4 __attribute__((ext_vector_type(4)));
typedef bf16x8 bf16x8_ma __attribute__((may_alias));
typedef f32x4  f32x4_ma  __attribute__((may_alias));
typedef uint2  uint2_ma  __attribute__((may_alias));
typedef unsigned       u32_ma __attribute__((may_alias));
typedef unsigned short u16_ma __attribute__((may_alias));

__constant__ int NEI5c[NN][5] = {
  {0,1,2,3,0},   {1,0,4,1,1},   {2,0,5,2,2},   {3,0,6,3,3},
  {4,1,7,4,4},   {5,2,8,5,5},   {6,3,9,6,6},   {7,4,10,7,7},
  {8,5,11,8,8},  {9,6,12,13,14},{10,7,10,10,10},{11,8,11,11,11},
  {12,9,15,12,12},{13,9,16,13,13},{14,9,17,14,14},{15,12,15,15,15},
  {16,13,18,16,16},{17,14,19,17,17},{18,16,20,18,18},{19,17,21,19,19},
  {20,18,22,20,20},{21,19,23,21,21},{22,20,22,22,22},{23,21,23,23,23}
};
__constant__ int DEGc[NN] = {4,3,3,3,3,3,3,3,3,5,2,2,3,3,3,2,3,3,3,3,3,3,2,2};

__device__ __forceinline__ void barrier_lgkm() {
  asm volatile("s_waitcnt lgkmcnt(0)" ::: "memory");
  __builtin_amdgcn_s_barrier();
  asm volatile("" ::: "memory");   // block load-hoisting above the barrier
}

// ---------------- prep: weights -> A-fragment (w^T) hi/lo planes -------------
// dwords: L0 [24][1][4][2][64][4] @0      L1 [24][2][4][2][64][4] @49152
//         L2 [...] @147456               L3 [24][2][1][2][64][4] @245760
// frag element j=2*dw+e: w[k = kh*32 + 8*(lane>>4) + j][o = ot*16 + (lane&15)]
extern "C" __global__ void gnn_prep(const float* __restrict__ w0, const float* __restrict__ w1,
                                    const float* __restrict__ w2, const float* __restrict__ w3,
                                    unsigned* __restrict__ dst)
{
  int idx = blockIdx.x * 256 + threadIdx.x;
  if (idx >= PREP_TOT) return;
  const float* w; int KH, OT, kd, od, local;
  if (idx < 49152)       { local = idx;           w = w0; KH = 1; OT = 4; kd = 7;  od = 64; }
  else if (idx < 147456) { local = idx - 49152;   w = w1; KH = 2; OT = 4; kd = 64; od = 64; }
  else if (idx < 245760) { local = idx - 147456;  w = w2; KH = 2; OT = 4; kd = 64; od = 64; }
  else                   { local = idx - 245760;  w = w3; KH = 2; OT = 1; kd = 64; od = 13; }
  int per_n = KH * OT * 512;
  int n  = local / per_n;   int r = local % per_n;
  int kh = r / (OT * 512);  r %= OT * 512;
  int ot = r / 512;         r %= 512;
  int p  = r / 256;         r %= 256;
  int lane = r / 4;         int dw = r % 4;
  int o = ot * 16 + (lane & 15);
  unsigned outw = 0;
  #pragma unroll
  for (int e = 0; e < 2; ++e) {
    int k = kh * 32 + 8 * (lane >> 4) + dw * 2 + e;
    float v = (k < kd && o < od) ? w[(n * kd + k) * od + o] : 0.f;
    unsigned u = __float_as_uint(v);
    unsigned short val;
    if (p == 0) val = (unsigned short)(u >> 16);                 // trunc hi
    else {
      float hf = __uint_as_float(u & 0xFFFF0000u);
      val = (unsigned short)(__float_as_uint(v - hf) >> 16);     // trunc lo
    }
    outw |= ((unsigned)val) << (16 * e);
  }
  dst[idx] = outw;
}

// ---------------- main ----------------
// node region n (4096 B): AH rows [16][128B] @0, AL rows @2048 (bf16 act),
// aliased as HX rows [16][256B] fp32 (phase-separated). swz = (row&7)<<4.
// wave w: wp = w>>1 -> nodes 3wp..3wp+2; oth = w&1 -> ots {2oth, 2oth+1}.
template<int KH, int OT, bool RELU, bool LAST>
__device__ __forceinline__ void layerF(const unsigned* __restrict__ bw,
                                       const float* __restrict__ aw,
                                       const float* __restrict__ bias,
                                       char* __restrict__ LB,
                                       int c15, int g, int wp, int oth,
                                       float* __restrict__ out, long base)
{
  constexpr int OTL = (OT == 4) ? 2 : 1;
  const bool active = (OT == 4) || (oth == 0);
  const int swz = (c15 & 7) << 4;
  const int lane = (g << 4) | c15;
  const bf16x8* __restrict__ bp = (const bf16x8*)bw;
  f32x4 acc[3][OTL];

  // Phase A: per-node linears. D[row=o][col=b] = w^T x act  (split-3)
  if (active) {
    #pragma unroll
    for (int i = 0; i < 3; ++i) {
      const int n = wp * 3 + i;
      bf16x8 wh[KH][OTL], wl[KH][OTL];
      #pragma unroll
      for (int kh = 0; kh < KH; ++kh)
        #pragma unroll
        for (int otl = 0; otl < OTL; ++otl) {
          const int ot = (OT == 4) ? (2 * oth + otl) : 0;
          const int fi = (((n * KH + kh) * OT + ot) * 2) * 64 + lane;
          wh[kh][otl] = bp[fi];
          wl[kh][otl] = bp[fi + 64];
        }
      bf16x8 ah[KH], al[KH];
      char* actn = LB + n * 4096 + c15 * 128;
      #pragma unroll
      for (int kh = 0; kh < KH; ++kh) {
        const int cb = (64 * kh + 16 * g) ^ swz;
        ah[kh] = *(const bf16x8_ma*)(actn + cb);
        al[kh] = *(const bf16x8_ma*)(actn + 2048 + cb);
      }
      #pragma unroll
      for (int otl = 0; otl < OTL; ++otl) {
        f32x4 c = {0.f, 0.f, 0.f, 0.f};
        #pragma unroll
        for (int kh = 0; kh < KH; ++kh) {
          c = __builtin_amdgcn_mfma_f32_16x16x32_bf16(wh[kh][otl], ah[kh], c, 0, 0, 0);
          c = __builtin_amdgcn_mfma_f32_16x16x32_bf16(wl[kh][otl], ah[kh], c, 0, 0, 0);
          c = __builtin_amdgcn_mfma_f32_16x16x32_bf16(wh[kh][otl], al[kh], c, 0, 0, 0);
        }
        acc[i][otl] = c;
      }
    }
  }
  barrier_lgkm();          // A->B: pair-wave still reading act rows we clobber

  // Phase B: publish h (fp32) into node region (aliased over act)
  if (active) {
    #pragma unroll
    for (int i = 0; i < 3; ++i) {
      char* hxn = LB + (wp * 3 + i) * 4096 + c15 * 256;
      #pragma unroll
      for (int otl = 0; otl < OTL; ++otl) {
        const int ot = (OT == 4) ? (2 * oth + otl) : 0;
        *(f32x4_ma*)(hxn + ((64 * ot + 16 * g) ^ swz)) = acc[i][otl];
      }
    }
  }
  barrier_lgkm();          // B->C

  // Phase C: tree aggregation (fp32 float4 FMA on neighbors' h)
  f32x4 st[3][OTL];
  if (active) {
    #pragma unroll
    for (int i = 0; i < 3; ++i) {
      const int m = wp * 3 + i;
      #pragma unroll
      for (int otl = 0; otl < OTL; ++otl) {
        if (LAST) {
          #pragma unroll
          for (int r = 0; r < 4; ++r) {
            const int o = 4 * g + r;
            st[i][otl][r] = (o < 13) ? bias[o] : 0.f;
          }
        } else {
          const int ot = 2 * oth + otl;
          const float4 bv = *(const float4*)&bias[ot * 16 + 4 * g];
          st[i][otl][0] = bv.x; st[i][otl][1] = bv.y;
          st[i][otl][2] = bv.z; st[i][otl][3] = bv.w;
        }
      }
      const int deg = DEGc[m];
      for (int j = 0; j < deg; ++j) {          // wave-uniform trip count
        const int nb = NEI5c[m][j];
        const float sw = aw[m * NN + nb];
        const char* hxn = LB + nb * 4096 + c15 * 256;
        #pragma unroll
        for (int otl = 0; otl < OTL; ++otl) {
          const int ot = (OT == 4) ? (2 * oth + otl) : 0;
          const f32x4 u = *(const f32x4_ma*)(hxn + ((64 * ot + 16 * g) ^ swz));
          st[i][otl][0] = fmaf(sw, u[0], st[i][otl][0]);
          st[i][otl][1] = fmaf(sw, u[1], st[i][otl][1]);
          st[i][otl][2] = fmaf(sw, u[2], st[i][otl][2]);
          st[i][otl][3] = fmaf(sw, u[3], st[i][otl][3]);
        }
      }
      if (RELU) {
        #pragma unroll
        for (int otl = 0; otl < OTL; ++otl) {
          st[i][otl][0] = fmaxf(st[i][otl][0], 0.f);
          st[i][otl][1] = fmaxf(st[i][otl][1], 0.f);
          st[i][otl][2] = fmaxf(st[i][otl][2], 0.f);
          st[i][otl][3] = fmaxf(st[i][otl][3], 0.f);
        }
      }
    }
  }

  if (!LAST) {
    barrier_lgkm();        // C->D: all HX reads done before act overwrites h
    // Phase D: write next-layer act (trunc hi/lo, b64 vectorized)
    #pragma unroll
    for (int i = 0; i < 3; ++i) {
      char* actn = LB + (wp * 3 + i) * 4096 + c15 * 128;
      #pragma unroll
      for (int otl = 0; otl < OTL; ++otl) {
        const int ot = 2 * oth + otl;
        const unsigned u0 = __float_as_uint(st[i][otl][0]);
        const unsigned u1 = __float_as_uint(st[i][otl][1]);
        const unsigned u2 = __float_as_uint(st[i][otl][2]);
        const unsigned u3 = __float_as_uint(st[i][otl][3]);
        const float d0 = st[i][otl][0] - __uint_as_float(u0 & 0xFFFF0000u);
        const float d1 = st[i][otl][1] - __uint_as_float(u1 & 0xFFFF0000u);
        const float d2 = st[i][otl][2] - __uint_as_float(u2 & 0xFFFF0000u);
        const float d3 = st[i][otl][3] - __uint_as_float(u3 & 0xFFFF0000u);
        uint2 hv, lv;
        hv.x = (u0 >> 16) | (u1 & 0xFFFF0000u);
        hv.y = (u2 >> 16) | (u3 & 0xFFFF0000u);
        lv.x = (__float_as_uint(d0) >> 16) | (__float_as_uint(d1) & 0xFFFF0000u);
        lv.y = (__float_as_uint(d2) >> 16) | (__float_as_uint(d3) & 0xFFFF0000u);
        const int cb = (32 * ot + 8 * g) ^ swz;
        *(uint2_ma*)(actn + cb) = hv;
        *(uint2_ma*)(actn + 2048 + cb) = lv;
      }
    }
    barrier_lgkm();        // D->A: next phase A reads cols written by pair-wave
  } else {
    if (active) {
      #pragma unroll
      for (int i = 0; i < 3; ++i) {
        const int m = wp * 3 + i;
        float* po = out + (base + c15) * 312 + m * 13;
        #pragma unroll
        for (int r = 0; r < 4; ++r) {
          const int o = 4 * g + r;
          if (o < 13) po[o] = st[i][0][r];
        }
      }
    }
  }
}

extern "C" __global__ __launch_bounds__(NT, 4)
void gnn_main(const float* __restrict__ x,
              const float* __restrict__ aw0, const float* __restrict__ aw1,
              const float* __restrict__ aw2, const float* __restrict__ aw3,
              const float* __restrict__ b0, const float* __restrict__ b1,
              const float* __restrict__ b2, const float* __restrict__ b3,
              const unsigned* __restrict__ bw, float* __restrict__ out)
{
  __shared__ __align__(16) char LB[NN * 4096];   // 98304 B
  const int t = threadIdx.x;
  const int c15 = t & 15, g = (t >> 4) & 3;
  const int w = t >> 6, wp = w >> 1, oth = w & 1;
  const long base = (long)blockIdx.x * MB;

  // stage x -> act planes (root masked, trunc split)
  for (int i2 = t; i2 < MB * NN * 7; i2 += NT) {
    const int b = i2 / 168, r = i2 % 168, n = r / 7, k = r % 7;
    float v = x[base * 168 + i2];                 // coalesced
    if (n == 0) v = 0.f;
    const unsigned u = __float_as_uint(v);
    const float hf = __uint_as_float(u & 0xFFFF0000u);
    const unsigned short h = (unsigned short)(u >> 16);
    const unsigned short l = (unsigned short)(__float_as_uint(v - hf) >> 16);
    char* actn = LB + n * 4096 + b * 128;
    const int cb = (2 * k) ^ ((b & 7) << 4);
    *(u16_ma*)(actn + cb) = h;
    *(u16_ma*)(actn + 2048 + cb) = l;
  }
  // zero k = 7..31 (layer-0 K window)
  for (int i2 = t; i2 < NN * MB; i2 += NT) {
    const int n = i2 / 16, b = i2 % 16;
    char* actn = LB + n * 4096 + b * 128;
    const int s = (b & 7) << 4;
    *(u16_ma*)(actn + (14 ^ s)) = 0;
    *(u16_ma*)(actn + 2048 + (14 ^ s)) = 0;
    #pragma unroll
    for (int k = 8; k < 32; k += 2) {
      const int cb = (2 * k) ^ s;
      *(u32_ma*)(actn + cb) = 0;
      *(u32_ma*)(actn + 2048 + cb) = 0;
    }
  }
  barrier_lgkm();

  layerF<1, 4, true,  false>(bw,          aw0, b0, LB, c15, g, wp, oth, out, base);
  layerF<2, 4, true,  false>(bw + 49152,  aw1, b1, LB, c15, g, wp, oth, out, base);
  layerF<2, 4, true,  false>(bw + 147456, aw2, b2, LB, c15, g, wp, oth, out, base);
  layerF<2, 1, false, true >(bw + 245760, aw3, b3, LB, c15, g, wp, oth, out, base);
}

extern "C" void kernel_launch(void* const* d_in, const int* in_sizes, int n_in,
                              void* d_out, int out_size, void* d_ws, size_t ws_size,
                              hipStream_t stream)
{
  const float* x   = (const float*)d_in[0];
  const float* w0  = (const float*)d_in[1];
  const float* w1  = (const float*)d_in[2];
  const float* w2  = (const float*)d_in[3];
  const float* w3  = (const float*)d_in[4];
  const float* aw0 = (const float*)d_in[5];
  const float* aw1 = (const float*)d_in[6];
  const float* aw2 = (const float*)d_in[7];
  const float* aw3 = (const float*)d_in[8];
  const float* b0  = (const float*)d_in[9];
  const float* b1  = (const float*)d_in[10];
  const float* b2  = (const float*)d_in[11];
  const float* b3  = (const float*)d_in[12];
  float* out = (float*)d_out;
  unsigned* bw = (unsigned*)d_ws;               // 1,081,344 B of workspace

  const int B = in_sizes[0] / (NN * 7);         // 65536
  const int grid = B / MB;                      // 4096

  gnn_prep<<<(PREP_TOT + 255) / 256, 256, 0, stream>>>(w0, w1, w2, w3, bw);
  gnn_main<<<grid, NT, 0, stream>>>(x, aw0, aw1, aw2, aw3, b0, b1, b2, b3, bw, out);
}